// Round 12
// baseline (1780.414 us; speedup 1.0000x reference)
//
#include <hip/hip_runtime.h>
#include <hip/hip_bf16.h>
#include <hip/hip_fp16.h>

#define N_NODES 100000
#define N_EDGES 3200000
#define ET (N_EDGES + N_NODES)   // edges + self loops
#define F_IN 500
#define H1 8
#define C1 8
#define F1 64                    // H1*C1
#define C2 7

#define BSH 6                    // 64 nodes per bucket
#define NB ((N_NODES + 63) / 64) // 1563
#define FB 64                    // partition blocks
#define FCHUNK ((ET + FB - 1) / FB)

typedef __attribute__((ext_vector_type(8))) short short8;
typedef __attribute__((ext_vector_type(4))) float f32x4;

__device__ __forceinline__ unsigned short f2bf(float f) {
    const unsigned u = __float_as_uint(f);
    return (unsigned short)((u + 0x7FFFu + ((u >> 16) & 1u)) >> 16);
}

// ---------------- CSR build: atomic-free 3-phase partition ----------------
__global__ __launch_bounds__(1024) void fill_count(const int* __restrict__ ei,
                                                   int* __restrict__ cntmat) {
    __shared__ int hist[NB];
    const int t = threadIdx.x, blk = blockIdx.x;
    for (int i = t; i < NB; i += 1024) hist[i] = 0;
    __syncthreads();
    const int s0 = blk * FCHUNK;
    const int s1 = min(s0 + FCHUNK, ET);
    for (int i = s0 + t; i < s1; i += 1024) {
        const int dst = (i < N_EDGES) ? ei[N_EDGES + i] : (i - N_EDGES);
        atomicAdd(&hist[dst >> BSH], 1);
    }
    __syncthreads();
    int* row = cntmat + (size_t)blk * NB;
    for (int i = t; i < NB; i += 1024) row[i] = hist[i];
}

__global__ __launch_bounds__(1024) void scan2(const int* __restrict__ cntmat,
                                              int* __restrict__ boff,
                                              int* __restrict__ basemat) {
    __shared__ int tot[2048];
    __shared__ int wsum[16];
    const int t = threadIdx.x;
    const int lane = t & 63;
    const int w = t >> 6;
    for (int b = t; b < 2048; b += 1024) {
        int s = 0;
        if (b < NB)
            for (int j = 0; j < FB; ++j) s += cntmat[(size_t)j * NB + b];
        tot[b] = s;
    }
    __syncthreads();
    int running = 0;
    for (int t0 = 0; t0 < 2048; t0 += 1024) {
        const int v = tot[t0 + t];
        int sc = v;
#pragma unroll
        for (int d = 1; d < 64; d <<= 1) {
            int u = __shfl_up(sc, d);
            if (lane >= d) sc += u;
        }
        if (lane == 63) wsum[w] = sc;
        __syncthreads();
        if (t < 16) {
            int ws = wsum[t];
#pragma unroll
            for (int d = 1; d < 16; d <<= 1) {
                int u = __shfl_up(ws, d);
                if (t >= d) ws += u;
            }
            wsum[t] = ws;
        }
        __syncthreads();
        const int excl = running + (w ? wsum[w - 1] : 0) + sc - v;
        if (t0 + t < NB) boff[t0 + t] = excl;
        const int tt = wsum[15];
        __syncthreads();
        tot[t0 + t] = excl;
        running += tt;
    }
    if (t == 0) boff[NB] = running;     // == ET
    __syncthreads();
    for (int b = t; b < NB; b += 1024) {
        int run = tot[b];
        for (int j = 0; j < FB; ++j) {
            basemat[(size_t)j * NB + b] = run;
            run += cntmat[(size_t)j * NB + b];
        }
    }
}

__global__ __launch_bounds__(1024) void fill_scatter(const int* __restrict__ ei,
                                                     const int* __restrict__ basemat,
                                                     unsigned int* __restrict__ ebuf) {
    __shared__ int cur[NB];
    const int t = threadIdx.x, blk = blockIdx.x;
    const int* row = basemat + (size_t)blk * NB;
    for (int i = t; i < NB; i += 1024) cur[i] = row[i];
    __syncthreads();
    const int s0 = blk * FCHUNK;
    const int s1 = min(s0 + FCHUNK, ET);
    for (int i = s0 + t; i < s1; i += 1024) {
        int src, dst;
        if (i < N_EDGES) { src = ei[i]; dst = ei[N_EDGES + i]; }
        else             { src = dst = i - N_EDGES; }
        const int b = dst >> BSH;
        const int p = atomicAdd(&cur[b], 1);
        ebuf[p] = (unsigned)src | ((unsigned)(dst & 63) << 17);
    }
}

// ---------------- W prep: W1[500][64] -> bf16 fragment-packed wpk ----------------
__global__ __launch_bounds__(256) void wprep(const float* __restrict__ W1,
                                             short* __restrict__ wpk) {
    const int idx = blockIdx.x * 256 + threadIdx.x;
    if (idx >= 32768) return;
    const int j = idx & 7;
    const int l = (idx >> 3) & 63;
    const int f = (idx >> 9) & 3;
    const int ks = idx >> 11;
    const int k = ks * 32 + ((l >> 4) << 3) + j;
    const int col = f * 16 + (l & 15);
    const float fv = (k < F_IN) ? W1[k * F1 + col] : 0.f;
    wpk[idx] = (short)f2bf(fv);
}

// ---------------- layer 1 GEMM: MFMA, split-A (hi+lo) x bf16-W ----------------
__global__ __launch_bounds__(256) void gemm1_kernel(
    const float* __restrict__ x, const short* __restrict__ wpk,
    const float* __restrict__ a_src, const float* __restrict__ a_dst,
    __half* __restrict__ h1, float* __restrict__ as1, float* __restrict__ ad1)
{
    const int t = threadIdx.x;
    const int l = t & 63;
    const int w = t >> 6;
    const int row0 = blockIdx.x * 64 + w * 16;
    const int r = l & 15;
    const int koff = (l >> 4) * 8;
    const float* __restrict__ xp =
        x + (size_t)min(row0 + r, N_NODES - 1) * F_IN + koff;
    const short* __restrict__ wl = wpk + (l << 3);

    f32x4 acc[4];
#pragma unroll
    for (int f = 0; f < 4; ++f) acc[f] = (f32x4){0.f, 0.f, 0.f, 0.f};

    float4 va = *(const float4*)(xp);
    float4 vb = *(const float4*)(xp + 4);
    short8 bcur[4];
#pragma unroll
    for (int f = 0; f < 4; ++f)
        bcur[f] = *(const short8*)(wl + (f << 9));

    for (int ks = 0; ks < 16; ++ks) {
        float v[8];
        v[0] = va.x; v[1] = va.y; v[2] = va.z; v[3] = va.w;
        v[4] = vb.x; v[5] = vb.y; v[6] = vb.z; v[7] = vb.w;
        if (ks < 14) {
            va = *(const float4*)(xp + (ks + 1) * 32);
            vb = *(const float4*)(xp + (ks + 1) * 32 + 4);
        } else if (ks == 14) {
            float tv[8];
#pragma unroll
            for (int j = 0; j < 8; ++j)
                tv[j] = (koff + j < 20) ? xp[480 + j] : 0.f;
            va = make_float4(tv[0], tv[1], tv[2], tv[3]);
            vb = make_float4(tv[4], tv[5], tv[6], tv[7]);
        }
        short8 bnext[4];
        if (ks < 15) {
#pragma unroll
            for (int f = 0; f < 4; ++f)
                bnext[f] = *(const short8*)(wl + (((ks + 1) * 4 + f) << 9));
        }
        short8 ah, al;
#pragma unroll
        for (int j = 0; j < 8; ++j) {
            const unsigned short h = f2bf(v[j]);
            ah[j] = (short)h;
            al[j] = (short)f2bf(v[j] - __uint_as_float((unsigned)h << 16));
        }
#pragma unroll
        for (int f = 0; f < 4; ++f) {
            acc[f] = __builtin_amdgcn_mfma_f32_16x16x32_bf16(ah, bcur[f], acc[f], 0, 0, 0);
            acc[f] = __builtin_amdgcn_mfma_f32_16x16x32_bf16(al, bcur[f], acc[f], 0, 0, 0);
        }
        if (ks < 15) {
#pragma unroll
            for (int f = 0; f < 4; ++f) bcur[f] = bnext[f];
        }
    }

    // epilogue: D[row][col], row = row0 + (l>>4)*4 + reg, col = f*16 + (l&15)
    const int g = l >> 4;
    const int p = r >> 3;
    float asv[4], adv[4];
#pragma unroll
    for (int f = 0; f < 4; ++f) {
        asv[f] = a_src[f * 16 + r];
        adv[f] = a_dst[f * 16 + r];
    }
#pragma unroll
    for (int f = 0; f < 4; ++f) {
#pragma unroll
        for (int reg = 0; reg < 4; ++reg) {
            const int row = row0 + g * 4 + reg;
            const float hv = acc[f][reg];
            if (row < N_NODES)
                h1[(size_t)row * F1 + f * 16 + r] = __float2half(hv);
            float ps = hv * asv[f];
            float pd = hv * adv[f];
            ps += __shfl_xor(ps, 1); ps += __shfl_xor(ps, 2); ps += __shfl_xor(ps, 4);
            pd += __shfl_xor(pd, 1); pd += __shfl_xor(pd, 2); pd += __shfl_xor(pd, 4);
            if ((l & 7) == 0 && row < N_NODES) {
                as1[row * H1 + f * 2 + p] = ps;
                ad1[row * H1 + f * 2 + p] = pd;
            }
        }
    }
}

// ---------------- layer 1 aggregation: block per bucket, LDS accumulators ----
// No sort needed: edges arrive bucket-grouped in ebuf. Lane l computes e/exp
// for (edge l&7, head l>>3); contributions scatter into acc[dst][l] via
// ds_add_f32 (bank l%32 -> 2-way, free). den[dst][head] from 8 lanes.
__global__ __launch_bounds__(256) void agg1_kernel(
    const int* __restrict__ boff, const unsigned int* __restrict__ ebuf,
    const __half* __restrict__ h1, const float* __restrict__ as1,
    const float* __restrict__ ad1, const float* __restrict__ b1,
    float* __restrict__ hout)
{
    __shared__ float acc[64 * 64];
    __shared__ float den[64 * 8];
    const int t = threadIdx.x;
    const int b = blockIdx.x;
    const int l = t & 63;
    const int w = t >> 6;
    const int e0 = boff[b];
    const int cnt = boff[b + 1] - e0;

    for (int i = t; i < 64 * 64; i += 256) acc[i] = 0.f;
    for (int i = t; i < 64 * 8; i += 256) den[i] = 0.f;
    __syncthreads();

    const int jsub = l & 7;
    const int hsub = l >> 3;
    const int pbase = l & 56;
    const int nb0 = b << 6;

    for (int j0 = w * 8; j0 < cnt; j0 += 32) {
        const int jc = min(j0 + jsub, cnt - 1);
        const unsigned eb = ebuf[e0 + jc];
        const int s_l = (int)(eb & 0x1FFFFu);
        const int d_l = (int)(eb >> 17);
        float e = as1[(s_l << 3) + hsub] + ad1[((nb0 + d_l) << 3) + hsub];
        e = fmaxf(e, 0.2f * e);
        const float p_l = __expf(e);
        const int rem = cnt - j0;
        if (rem >= 8) {
#pragma unroll
            for (int j = 0; j < 8; ++j) {
                const unsigned ej = (unsigned)__builtin_amdgcn_readlane((int)eb, j);
                const int s_j = (int)(ej & 0x1FFFFu);
                const int d_j = (int)(ej >> 17);
                const float p = __shfl(p_l, pbase + j);
                const float v = __half2float(h1[((size_t)(unsigned)s_j << 6) + l]);
                atomicAdd(&acc[(d_j << 6) + l], p * v);
                if (jsub == 0) atomicAdd(&den[(d_j << 3) + hsub], p);
            }
        } else {
#pragma unroll
            for (int j = 0; j < 8; ++j) {
                if (j < rem) {
                    const unsigned ej = (unsigned)__builtin_amdgcn_readlane((int)eb, j);
                    const int s_j = (int)(ej & 0x1FFFFu);
                    const int d_j = (int)(ej >> 17);
                    const float p = __shfl(p_l, pbase + j);
                    const float v = __half2float(h1[((size_t)(unsigned)s_j << 6) + l]);
                    atomicAdd(&acc[(d_j << 6) + l], p * v);
                    if (jsub == 0) atomicAdd(&den[(d_j << 3) + hsub], p);
                }
            }
        }
    }
    __syncthreads();
    // finalize: thread t -> node t>>2, 16-col quarter (t&3)
    const int nd = t >> 2;
    const int gn = nb0 + nd;
    if (gn < N_NODES) {
        const int c0 = (t & 3) << 4;
#pragma unroll
        for (int i = 0; i < 16; ++i) {
            const int c = c0 + i;
            hout[((size_t)gn << 6) + c] =
                acc[(nd << 6) + c] / den[(nd << 3) + (c >> 3)] + b1[c];
        }
    }
}

// ---------------- layer 2 GEMM + attention coefficients ----------------
__global__ __launch_bounds__(256) void gemm2_kernel(
    const float* __restrict__ hin, const float* __restrict__ W2,
    const float* __restrict__ a_src, const float* __restrict__ a_dst,
    float* __restrict__ h2p, float* __restrict__ as2, float* __restrict__ ad2)
{
    __shared__ float w2s[F1 * C2];
    __shared__ float as_s[C2], ad_s[C2];
    for (int i = threadIdx.x; i < F1 * C2; i += blockDim.x) w2s[i] = W2[i];
    if (threadIdx.x < C2) { as_s[threadIdx.x] = a_src[threadIdx.x]; ad_s[threadIdx.x] = a_dst[threadIdx.x]; }
    __syncthreads();

    int n = blockIdx.x * blockDim.x + threadIdx.x;
    if (n >= N_NODES) return;
    float acc[C2];
#pragma unroll
    for (int c = 0; c < C2; ++c) acc[c] = 0.f;
    const float* hp = hin + (size_t)n * F1;
    for (int k = 0; k < F1; k += 4) {
        const float4 hv = *(const float4*)(hp + k);
#pragma unroll
        for (int c = 0; c < C2; ++c) {
            acc[c] = fmaf(hv.x, w2s[(k + 0) * C2 + c], acc[c]);
            acc[c] = fmaf(hv.y, w2s[(k + 1) * C2 + c], acc[c]);
            acc[c] = fmaf(hv.z, w2s[(k + 2) * C2 + c], acc[c]);
            acc[c] = fmaf(hv.w, w2s[(k + 3) * C2 + c], acc[c]);
        }
    }
    float s = 0.f, d = 0.f;
#pragma unroll
    for (int c = 0; c < C2; ++c) {
        s = fmaf(acc[c], as_s[c], s);
        d = fmaf(acc[c], ad_s[c], d);
    }
    float4* o = (float4*)(h2p + (size_t)n * 8);
    o[0] = make_float4(acc[0], acc[1], acc[2], acc[3]);
    o[1] = make_float4(acc[4], acc[5], acc[6], 0.f);
    as2[n] = s;
    ad2[n] = d;
}

// ---------------- layer 2 aggregation: block per bucket + log_softmax -------
// lane = (edge l>>3, slot l&7); slot 7 accumulates the denominator.
__global__ __launch_bounds__(256) void agg2_kernel(
    const int* __restrict__ boff, const unsigned int* __restrict__ ebuf,
    const float* __restrict__ h2p, const float* __restrict__ as2,
    const float* __restrict__ ad2, const float* __restrict__ b2,
    float* __restrict__ out)
{
    __shared__ float acc[64 * 8];
    const int t = threadIdx.x;
    const int b = blockIdx.x;
    const int l = t & 63;
    const int w = t >> 6;
    const int e0 = boff[b];
    const int cnt = boff[b + 1] - e0;
    for (int i = t; i < 512; i += 256) acc[i] = 0.f;
    __syncthreads();

    const int jq = l >> 3;
    const int c = l & 7;
    const int nb0 = b << 6;
    for (int j0 = w * 8; j0 < cnt; j0 += 32) {
        const int j = j0 + jq;
        if (j < cnt) {
            const unsigned eb = ebuf[e0 + j];
            const int s = (int)(eb & 0x1FFFFu);
            const int d = (int)(eb >> 17);
            float e = as2[s] + ad2[nb0 + d];
            e = fmaxf(e, 0.2f * e);
            const float p = __expf(e);
            const float v = (c < 7) ? h2p[((size_t)s << 3) + c] : 1.f;
            atomicAdd(&acc[(d << 3) + c], p * v);
        }
    }
    __syncthreads();
    if (t < 64) {
        const int gn = nb0 + t;
        if (gn < N_NODES) {
            const float inv = 1.f / acc[(t << 3) + 7];
            float v[C2];
            float mx = -1e30f;
#pragma unroll
            for (int cc = 0; cc < C2; ++cc) {
                v[cc] = acc[(t << 3) + cc] * inv + b2[cc];
                mx = fmaxf(mx, v[cc]);
            }
            float se = 0.f;
#pragma unroll
            for (int cc = 0; cc < C2; ++cc) se += __expf(v[cc] - mx);
            const float lse = __logf(se) + mx;
#pragma unroll
            for (int cc = 0; cc < C2; ++cc) out[gn * C2 + cc] = v[cc] - lse;
        }
    }
}

extern "C" void kernel_launch(void* const* d_in, const int* in_sizes, int n_in,
                              void* d_out, int out_size, void* d_ws, size_t ws_size,
                              hipStream_t stream) {
    const float* x      = (const float*)d_in[0];
    const int*   ei     = (const int*)  d_in[1];
    const float* W1     = (const float*)d_in[2];
    const float* a_src1 = (const float*)d_in[3];
    const float* a_dst1 = (const float*)d_in[4];
    const float* b1     = (const float*)d_in[5];
    const float* W2     = (const float*)d_in[6];
    const float* a_src2 = (const float*)d_in[7];
    const float* a_dst2 = (const float*)d_in[8];
    const float* b2     = (const float*)d_in[9];
    float* out = (float*)d_out;

    char* ws = (char*)d_ws;
    size_t off = 0;
    auto alloc = [&](size_t bytes) -> void* {
        void* p = ws + off;
        off += (bytes + 255) & ~(size_t)255;
        return p;
    };
    int*          boff    = (int*)   alloc((size_t)(NB + 1) * sizeof(int));
    int*          cntmat  = (int*)   alloc((size_t)FB * NB * sizeof(int));
    int*          basemat = (int*)   alloc((size_t)FB * NB * sizeof(int));
    unsigned int* ebuf    = (unsigned int*)alloc((size_t)ET * sizeof(unsigned int));
    short*        wpk     = (short*) alloc((size_t)32768 * sizeof(short));
    __half*       h1      = (__half*)alloc((size_t)N_NODES * F1 * sizeof(__half));
    float*        as1     = (float*) alloc((size_t)N_NODES * H1 * sizeof(float));
    float*        ad1     = (float*) alloc((size_t)N_NODES * H1 * sizeof(float));
    float*        hout1   = (float*) alloc((size_t)N_NODES * F1 * sizeof(float));
    float*        h2p     = (float*) alloc((size_t)N_NODES * 8 * sizeof(float));
    float*        as2     = (float*) alloc((size_t)N_NODES * sizeof(float));
    float*        ad2     = (float*) alloc((size_t)N_NODES * sizeof(float));

    wprep<<<128, 256, 0, stream>>>(W1, wpk);
    fill_count<<<FB, 1024, 0, stream>>>(ei, cntmat);
    scan2<<<1, 1024, 0, stream>>>(cntmat, boff, basemat);
    fill_scatter<<<FB, 1024, 0, stream>>>(ei, basemat, ebuf);
    gemm1_kernel<<<(N_NODES + 63) / 64, 256, 0, stream>>>(x, wpk, a_src1, a_dst1, h1, as1, ad1);
    agg1_kernel<<<NB, 256, 0, stream>>>(boff, ebuf, h1, as1, ad1, b1, hout1);
    gemm2_kernel<<<(N_NODES + 255) / 256, 256, 0, stream>>>(hout1, W2, a_src2, a_dst2, h2p, as2, ad2);
    agg2_kernel<<<NB, 256, 0, stream>>>(boff, ebuf, h2p, as2, ad2, b2, out);
}

// Round 13
// 387.921 us; speedup vs baseline: 4.5896x; 4.5896x over previous
//
#include <hip/hip_runtime.h>
#include <hip/hip_bf16.h>
#include <hip/hip_fp16.h>

#define N_NODES 100000
#define N_EDGES 3200000
#define ET (N_EDGES + N_NODES)   // edges + self loops
#define F_IN 500
#define H1 8
#define C1 8
#define F1 64                    // H1*C1
#define C2 7

#define BSH 6                    // 64 nodes per bucket
#define NB ((N_NODES + 63) / 64) // 1563
#define CAP 6144                 // LDS edge capacity per bucket (avg ~2111)
#define FB 64                    // partition blocks
#define FCHUNK ((ET + FB - 1) / FB)

typedef __attribute__((ext_vector_type(8))) short short8;
typedef __attribute__((ext_vector_type(4))) float f32x4;

__device__ __forceinline__ unsigned short f2bf(float f) {
    const unsigned u = __float_as_uint(f);
    return (unsigned short)((u + 0x7FFFu + ((u >> 16) & 1u)) >> 16);
}

// ---------------- CSR build: atomic-free 3-phase partition ----------------
__global__ __launch_bounds__(1024) void fill_count(const int* __restrict__ ei,
                                                   int* __restrict__ cntmat) {
    __shared__ int hist[NB];
    const int t = threadIdx.x, blk = blockIdx.x;
    for (int i = t; i < NB; i += 1024) hist[i] = 0;
    __syncthreads();
    const int s0 = blk * FCHUNK;
    const int s1 = min(s0 + FCHUNK, ET);
    for (int i = s0 + t; i < s1; i += 1024) {
        const int dst = (i < N_EDGES) ? ei[N_EDGES + i] : (i - N_EDGES);
        atomicAdd(&hist[dst >> BSH], 1);
    }
    __syncthreads();
    int* row = cntmat + (size_t)blk * NB;
    for (int i = t; i < NB; i += 1024) row[i] = hist[i];
}

__global__ __launch_bounds__(1024) void scan2(const int* __restrict__ cntmat,
                                              int* __restrict__ boff,
                                              int* __restrict__ basemat,
                                              int* __restrict__ rowptr) {
    __shared__ int tot[2048];
    __shared__ int wsum[16];
    const int t = threadIdx.x;
    const int lane = t & 63;
    const int w = t >> 6;
    for (int b = t; b < 2048; b += 1024) {
        int s = 0;
        if (b < NB)
            for (int j = 0; j < FB; ++j) s += cntmat[(size_t)j * NB + b];
        tot[b] = s;
    }
    __syncthreads();
    int running = 0;
    for (int t0 = 0; t0 < 2048; t0 += 1024) {
        const int v = tot[t0 + t];
        int sc = v;
#pragma unroll
        for (int d = 1; d < 64; d <<= 1) {
            int u = __shfl_up(sc, d);
            if (lane >= d) sc += u;
        }
        if (lane == 63) wsum[w] = sc;
        __syncthreads();
        if (t < 16) {
            int ws = wsum[t];
#pragma unroll
            for (int d = 1; d < 16; d <<= 1) {
                int u = __shfl_up(ws, d);
                if (t >= d) ws += u;
            }
            wsum[t] = ws;
        }
        __syncthreads();
        const int excl = running + (w ? wsum[w - 1] : 0) + sc - v;
        if (t0 + t < NB) boff[t0 + t] = excl;
        const int tt = wsum[15];
        __syncthreads();
        tot[t0 + t] = excl;
        running += tt;
    }
    if (t == 0) {
        boff[NB] = running;            // == ET
        rowptr[N_NODES] = running;
    }
    __syncthreads();
    for (int b = t; b < NB; b += 1024) {
        int run = tot[b];
        for (int j = 0; j < FB; ++j) {
            basemat[(size_t)j * NB + b] = run;
            run += cntmat[(size_t)j * NB + b];
        }
    }
}

__global__ __launch_bounds__(1024) void fill_scatter(const int* __restrict__ ei,
                                                     const int* __restrict__ basemat,
                                                     unsigned int* __restrict__ ebuf) {
    __shared__ int cur[NB];
    const int t = threadIdx.x, blk = blockIdx.x;
    const int* row = basemat + (size_t)blk * NB;
    for (int i = t; i < NB; i += 1024) cur[i] = row[i];
    __syncthreads();
    const int s0 = blk * FCHUNK;
    const int s1 = min(s0 + FCHUNK, ET);
    for (int i = s0 + t; i < s1; i += 1024) {
        int src, dst;
        if (i < N_EDGES) { src = ei[i]; dst = ei[N_EDGES + i]; }
        else             { src = dst = i - N_EDGES; }
        const int b = dst >> BSH;
        const int p = atomicAdd(&cur[b], 1);
        ebuf[p] = (unsigned)src | ((unsigned)(dst & 63) << 17);
    }
}

__global__ __launch_bounds__(256) void bucket_csr(const int* __restrict__ boff,
                                                  const unsigned int* __restrict__ ebuf,
                                                  int* __restrict__ col,
                                                  int* __restrict__ rowptr) {
    __shared__ unsigned int ebs[CAP];
    __shared__ int colb[CAP];
    __shared__ int hist[64], curs[64];
    const int b = blockIdx.x, t = threadIdx.x;
    const int e0 = boff[b], e1 = boff[b + 1];
    const int cnt = e1 - e0;
    if (t < 64) hist[t] = 0;
    __syncthreads();

    if (cnt <= CAP) {
        for (int i = t; i < cnt; i += 256) {
            const unsigned v = ebuf[e0 + i];
            ebs[i] = v;
            atomicAdd(&hist[v >> 17], 1);
        }
        __syncthreads();
        if (t < 64) {
            const int v = hist[t];
            int sc = v;
#pragma unroll
            for (int d = 1; d < 64; d <<= 1) {
                int u = __shfl_up(sc, d);
                if (t >= d) sc += u;
            }
            const int excl = sc - v;
            curs[t] = excl;
            const int n = (b << BSH) + t;
            if (n < N_NODES) rowptr[n] = e0 + excl;
        }
        __syncthreads();
        for (int i = t; i < cnt; i += 256) {
            const unsigned v = ebs[i];
            const int p = atomicAdd(&curs[v >> 17], 1);
            colb[p] = (int)(v & 0x1FFFFu);
        }
        __syncthreads();
        for (int i = t; i < cnt; i += 256) col[e0 + i] = colb[i];
    } else {
        for (int i = t; i < cnt; i += 256) atomicAdd(&hist[ebuf[e0 + i] >> 17], 1);
        __syncthreads();
        if (t < 64) {
            const int v = hist[t];
            int sc = v;
#pragma unroll
            for (int d = 1; d < 64; d <<= 1) {
                int u = __shfl_up(sc, d);
                if (t >= d) sc += u;
            }
            const int excl = sc - v;
            curs[t] = excl;
            const int n = (b << BSH) + t;
            if (n < N_NODES) rowptr[n] = e0 + excl;
        }
        __syncthreads();
        for (int i = t; i < cnt; i += 256) {
            const unsigned v = ebuf[e0 + i];
            const int p = atomicAdd(&curs[v >> 17], 1);
            col[e0 + p] = (int)(v & 0x1FFFFu);
        }
    }
}

// ---------------- W prep: W1[500][64] -> bf16 fragment-packed wpk ----------------
__global__ __launch_bounds__(256) void wprep(const float* __restrict__ W1,
                                             short* __restrict__ wpk) {
    const int idx = blockIdx.x * 256 + threadIdx.x;
    if (idx >= 32768) return;
    const int j = idx & 7;
    const int l = (idx >> 3) & 63;
    const int f = (idx >> 9) & 3;
    const int ks = idx >> 11;
    const int k = ks * 32 + ((l >> 4) << 3) + j;
    const int col = f * 16 + (l & 15);
    const float fv = (k < F_IN) ? W1[k * F1 + col] : 0.f;
    wpk[idx] = (short)f2bf(fv);
}

// ---------------- layer 1 GEMM: MFMA, split-A (hi+lo) x bf16-W ----------------
__global__ __launch_bounds__(256) void gemm1_kernel(
    const float* __restrict__ x, const short* __restrict__ wpk,
    const float* __restrict__ a_src, const float* __restrict__ a_dst,
    __half* __restrict__ h1, float* __restrict__ as1, float* __restrict__ ad1)
{
    const int t = threadIdx.x;
    const int l = t & 63;
    const int w = t >> 6;
    const int row0 = blockIdx.x * 64 + w * 16;
    const int r = l & 15;
    const int koff = (l >> 4) * 8;
    const float* __restrict__ xp =
        x + (size_t)min(row0 + r, N_NODES - 1) * F_IN + koff;
    const short* __restrict__ wl = wpk + (l << 3);

    f32x4 acc[4];
#pragma unroll
    for (int f = 0; f < 4; ++f) acc[f] = (f32x4){0.f, 0.f, 0.f, 0.f};

    float4 va = *(const float4*)(xp);
    float4 vb = *(const float4*)(xp + 4);
    short8 bcur[4];
#pragma unroll
    for (int f = 0; f < 4; ++f)
        bcur[f] = *(const short8*)(wl + (f << 9));

    for (int ks = 0; ks < 16; ++ks) {
        float v[8];
        v[0] = va.x; v[1] = va.y; v[2] = va.z; v[3] = va.w;
        v[4] = vb.x; v[5] = vb.y; v[6] = vb.z; v[7] = vb.w;
        if (ks < 14) {
            va = *(const float4*)(xp + (ks + 1) * 32);
            vb = *(const float4*)(xp + (ks + 1) * 32 + 4);
        } else if (ks == 14) {
            float tv[8];
#pragma unroll
            for (int j = 0; j < 8; ++j)
                tv[j] = (koff + j < 20) ? xp[480 + j] : 0.f;
            va = make_float4(tv[0], tv[1], tv[2], tv[3]);
            vb = make_float4(tv[4], tv[5], tv[6], tv[7]);
        }
        short8 bnext[4];
        if (ks < 15) {
#pragma unroll
            for (int f = 0; f < 4; ++f)
                bnext[f] = *(const short8*)(wl + (((ks + 1) * 4 + f) << 9));
        }
        short8 ah, al;
#pragma unroll
        for (int j = 0; j < 8; ++j) {
            const unsigned short h = f2bf(v[j]);
            ah[j] = (short)h;
            al[j] = (short)f2bf(v[j] - __uint_as_float((unsigned)h << 16));
        }
#pragma unroll
        for (int f = 0; f < 4; ++f) {
            acc[f] = __builtin_amdgcn_mfma_f32_16x16x32_bf16(ah, bcur[f], acc[f], 0, 0, 0);
            acc[f] = __builtin_amdgcn_mfma_f32_16x16x32_bf16(al, bcur[f], acc[f], 0, 0, 0);
        }
        if (ks < 15) {
#pragma unroll
            for (int f = 0; f < 4; ++f) bcur[f] = bnext[f];
        }
    }

    // epilogue: D[row][col], row = row0 + (l>>4)*4 + reg, col = f*16 + (l&15)
    const int g = l >> 4;
    const int p = r >> 3;
    float asv[4], adv[4];
#pragma unroll
    for (int f = 0; f < 4; ++f) {
        asv[f] = a_src[f * 16 + r];
        adv[f] = a_dst[f * 16 + r];
    }
#pragma unroll
    for (int f = 0; f < 4; ++f) {
#pragma unroll
        for (int reg = 0; reg < 4; ++reg) {
            const int row = row0 + g * 4 + reg;
            const float hv = acc[f][reg];
            if (row < N_NODES)
                h1[(size_t)row * F1 + f * 16 + r] = __float2half(hv);
            float ps = hv * asv[f];
            float pd = hv * adv[f];
            ps += __shfl_xor(ps, 1); ps += __shfl_xor(ps, 2); ps += __shfl_xor(ps, 4);
            pd += __shfl_xor(pd, 1); pd += __shfl_xor(pd, 2); pd += __shfl_xor(pd, 4);
            if ((l & 7) == 0 && row < N_NODES) {
                as1[row * H1 + f * 2 + p] = ps;
                ad1[row * H1 + f * 2 + p] = pd;
            }
        }
    }
}

// ---------------- layer 1 aggregation: wave per node, 8x8 + chunk prefetch ----
// Lane l computes e/exp for (edge l&7, head l>>3). Next chunk's col/as1 loads
// are issued during the current chunk's inner loop (off the critical path).
__global__ __launch_bounds__(256) void agg1_kernel(
    const int* __restrict__ rowptr, const int* __restrict__ col,
    const __half* __restrict__ h1, const float* __restrict__ as1,
    const float* __restrict__ ad1, const float* __restrict__ b1,
    float* __restrict__ hout)
{
    const int l = threadIdx.x & 63;
    const int n = (blockIdx.x << 2) + (threadIdx.x >> 6);
    if (n >= N_NODES) return;
    const int jsub = l & 7;          // lane's edge slot in chunk
    const int hsub = l >> 3;         // lane's head for e-compute
    const int pbase = l & 56;        // p for (edge j, my head) lives in lane pbase+j
    const int r0 = rowptr[n], r1 = rowptr[n + 1];
    const float adh = ad1[(n << 3) + hsub];

    float denom = 0.f, acc = 0.f;
    // prefetch chunk 0 (clamped; exact for full chunks)
    int s_n = col[min(r0 + jsub, r1 - 1)];
    float f_n = as1[(s_n << 3) + hsub];

    int j0 = r0;
    for (; j0 + 8 <= r1; j0 += 8) {
        const int s_l = s_n;
        const float f_l = f_n;
        const int jn = j0 + 8;
        if (jn < r1) {                       // prefetch next chunk
            s_n = col[min(jn + jsub, r1 - 1)];
            f_n = as1[(s_n << 3) + hsub];
        }
        float e = f_l + adh;
        e = fmaxf(e, 0.2f * e);
        const float p_l = __expf(e);
#pragma unroll
        for (int j = 0; j < 8; ++j) {
            const float p = __shfl(p_l, pbase + j);
            const int s_j = __builtin_amdgcn_readlane(s_l, j);
            const float v = __half2float(h1[((size_t)(unsigned)s_j << 6) + l]);
            denom += p;
            acc = fmaf(p, v, acc);
        }
    }
    // tail chunk (prefetched values already clamped correctly)
    if (j0 < r1) {
        float e = f_n + adh;
        e = fmaxf(e, 0.2f * e);
        const float p_l = __expf(e);
#pragma unroll
        for (int j = 0; j < 8; ++j) {
            if (j0 + j < r1) {
                const float p = __shfl(p_l, pbase + j);
                const int s_j = __builtin_amdgcn_readlane(s_n, j);
                const float v = __half2float(h1[((size_t)(unsigned)s_j << 6) + l]);
                denom += p;
                acc = fmaf(p, v, acc);
            }
        }
    }
    hout[(n << 6) + l] = acc / denom + b1[l];
}

// ---------------- layer 2 GEMM + attention coefficients ----------------
__global__ __launch_bounds__(256) void gemm2_kernel(
    const float* __restrict__ hin, const float* __restrict__ W2,
    const float* __restrict__ a_src, const float* __restrict__ a_dst,
    float* __restrict__ h2p, float* __restrict__ as2, float* __restrict__ ad2)
{
    __shared__ float w2s[F1 * C2];
    __shared__ float as_s[C2], ad_s[C2];
    for (int i = threadIdx.x; i < F1 * C2; i += blockDim.x) w2s[i] = W2[i];
    if (threadIdx.x < C2) { as_s[threadIdx.x] = a_src[threadIdx.x]; ad_s[threadIdx.x] = a_dst[threadIdx.x]; }
    __syncthreads();

    int n = blockIdx.x * blockDim.x + threadIdx.x;
    if (n >= N_NODES) return;
    float acc[C2];
#pragma unroll
    for (int c = 0; c < C2; ++c) acc[c] = 0.f;
    const float* hp = hin + (size_t)n * F1;
    for (int k = 0; k < F1; k += 4) {
        const float4 hv = *(const float4*)(hp + k);
#pragma unroll
        for (int c = 0; c < C2; ++c) {
            acc[c] = fmaf(hv.x, w2s[(k + 0) * C2 + c], acc[c]);
            acc[c] = fmaf(hv.y, w2s[(k + 1) * C2 + c], acc[c]);
            acc[c] = fmaf(hv.z, w2s[(k + 2) * C2 + c], acc[c]);
            acc[c] = fmaf(hv.w, w2s[(k + 3) * C2 + c], acc[c]);
        }
    }
    float s = 0.f, d = 0.f;
#pragma unroll
    for (int c = 0; c < C2; ++c) {
        s = fmaf(acc[c], as_s[c], s);
        d = fmaf(acc[c], ad_s[c], d);
    }
    float4* o = (float4*)(h2p + (size_t)n * 8);
    o[0] = make_float4(acc[0], acc[1], acc[2], acc[3]);
    o[1] = make_float4(acc[4], acc[5], acc[6], 0.f);
    as2[n] = s;
    ad2[n] = d;
}

// ---------------- layer 2 aggregation + bias + log_softmax (no-max) ----------
__global__ __launch_bounds__(256) void agg2_kernel(
    const int* __restrict__ rowptr, const int* __restrict__ col,
    const float* __restrict__ h2p, const float* __restrict__ as2,
    const float* __restrict__ ad2, const float* __restrict__ b2,
    float* __restrict__ out)
{
    const int gq = (blockIdx.x * 256 + threadIdx.x) >> 2;   // node
    const int q = threadIdx.x & 3;
    if (gq >= N_NODES) return;
    const int r0 = rowptr[gq], r1 = rowptr[gq + 1];
    const float adn = ad2[gq];

    float denom = 0.f;
    float a0 = 0, a1 = 0, a2 = 0, a3 = 0, a4 = 0, a5 = 0, a6 = 0;
    for (int j = r0 + q; j < r1; j += 4) {
        const int s = col[j];
        float e = as2[s] + adn;
        e = fmaxf(e, 0.2f * e);
        const float ex = __expf(e);
        const float4 va = *(const float4*)(h2p + (size_t)s * 8);
        const float4 vb = *(const float4*)(h2p + (size_t)s * 8 + 4);
        denom += ex;
        a0 = fmaf(ex, va.x, a0); a1 = fmaf(ex, va.y, a1);
        a2 = fmaf(ex, va.z, a2); a3 = fmaf(ex, va.w, a3);
        a4 = fmaf(ex, vb.x, a4); a5 = fmaf(ex, vb.y, a5);
        a6 = fmaf(ex, vb.z, a6);
    }
#pragma unroll
    for (int d = 1; d < 4; d <<= 1) {
        denom += __shfl_xor(denom, d);
        a0 += __shfl_xor(a0, d); a1 += __shfl_xor(a1, d);
        a2 += __shfl_xor(a2, d); a3 += __shfl_xor(a3, d);
        a4 += __shfl_xor(a4, d); a5 += __shfl_xor(a5, d);
        a6 += __shfl_xor(a6, d);
    }
    const float inv = 1.f / denom;
    float v0 = a0 * inv + b2[0], v1 = a1 * inv + b2[1];
    float v2 = a2 * inv + b2[2], v3 = a3 * inv + b2[3];
    float v4 = a4 * inv + b2[4], v5 = a5 * inv + b2[5];
    float v6 = a6 * inv + b2[6];
    float mx = fmaxf(fmaxf(fmaxf(v0, v1), fmaxf(v2, v3)), fmaxf(fmaxf(v4, v5), v6));
    const float se = __expf(v0 - mx) + __expf(v1 - mx) + __expf(v2 - mx) +
                     __expf(v3 - mx) + __expf(v4 - mx) + __expf(v5 - mx) +
                     __expf(v6 - mx);
    const float lse = __logf(se) + mx;
    const float wa = (q == 0) ? v0 : (q == 1) ? v1 : (q == 2) ? v2 : v3;
    const float wb = (q == 0) ? v4 : (q == 1) ? v5 : v6;
    out[gq * C2 + q] = wa - lse;
    if (q < 3) out[gq * C2 + q + 4] = wb - lse;
}

extern "C" void kernel_launch(void* const* d_in, const int* in_sizes, int n_in,
                              void* d_out, int out_size, void* d_ws, size_t ws_size,
                              hipStream_t stream) {
    const float* x      = (const float*)d_in[0];
    const int*   ei     = (const int*)  d_in[1];
    const float* W1     = (const float*)d_in[2];
    const float* a_src1 = (const float*)d_in[3];
    const float* a_dst1 = (const float*)d_in[4];
    const float* b1     = (const float*)d_in[5];
    const float* W2     = (const float*)d_in[6];
    const float* a_src2 = (const float*)d_in[7];
    const float* a_dst2 = (const float*)d_in[8];
    const float* b2     = (const float*)d_in[9];
    float* out = (float*)d_out;

    char* ws = (char*)d_ws;
    size_t off = 0;
    auto alloc = [&](size_t bytes) -> void* {
        void* p = ws + off;
        off += (bytes + 255) & ~(size_t)255;
        return p;
    };
    int*    rowptr  = (int*)   alloc((N_NODES + 1) * sizeof(int));
    int*    boff    = (int*)   alloc((size_t)(NB + 1) * sizeof(int));
    int*    cntmat  = (int*)   alloc((size_t)FB * NB * sizeof(int));
    int*    basemat = (int*)   alloc((size_t)FB * NB * sizeof(int));
    int*    colidx  = (int*)   alloc((size_t)ET * sizeof(int));
    short*  wpk     = (short*) alloc((size_t)32768 * sizeof(short));
    __half* h1      = (__half*)alloc((size_t)N_NODES * F1 * sizeof(__half));
    float*  as1     = (float*) alloc((size_t)N_NODES * H1 * sizeof(float));
    float*  ad1     = (float*) alloc((size_t)N_NODES * H1 * sizeof(float));
    float*  hout1   = (float*) alloc((size_t)N_NODES * F1 * sizeof(float));
    float*  h2p     = (float*) alloc((size_t)N_NODES * 8 * sizeof(float));
    float*  as2     = (float*) alloc((size_t)N_NODES * sizeof(float));
    float*  ad2     = (float*) alloc((size_t)N_NODES * sizeof(float));
    // ebuf aliases hout1 (hout1 is dead until agg1, which runs after bucket_csr)
    unsigned int* ebuf = (unsigned int*)hout1;

    wprep<<<128, 256, 0, stream>>>(W1, wpk);
    fill_count<<<FB, 1024, 0, stream>>>(ei, cntmat);
    scan2<<<1, 1024, 0, stream>>>(cntmat, boff, basemat, rowptr);
    fill_scatter<<<FB, 1024, 0, stream>>>(ei, basemat, ebuf);
    bucket_csr<<<NB, 256, 0, stream>>>(boff, ebuf, colidx, rowptr);
    gemm1_kernel<<<(N_NODES + 63) / 64, 256, 0, stream>>>(x, wpk, a_src1, a_dst1, h1, as1, ad1);
    agg1_kernel<<<(N_NODES + 3) / 4, 256, 0, stream>>>(rowptr, colidx, h1, as1, ad1, b1, hout1);
    gemm2_kernel<<<(N_NODES + 255) / 256, 256, 0, stream>>>(hout1, W2, a_src2, a_dst2, h2p, as2, ad2);
    agg2_kernel<<<(N_NODES * 4 + 255) / 256, 256, 0, stream>>>(rowptr, colidx, h2p, as2, ad2, b2, out);
}

// Round 14
// 339.073 us; speedup vs baseline: 5.2508x; 1.1441x over previous
//
#include <hip/hip_runtime.h>
#include <hip/hip_bf16.h>
#include <hip/hip_fp16.h>

#define N_NODES 100000
#define N_EDGES 3200000
#define ET (N_EDGES + N_NODES)   // edges + self loops
#define F_IN 500
#define H1 8
#define C1 8
#define F1 64                    // H1*C1
#define C2 7

#define BSH 6                    // 64 nodes per bucket
#define NB ((N_NODES + 63) / 64) // 1563
#define CAP2 4096                // LDS sorted-edge capacity per bucket (avg ~2111, max ~2300)
#define FB 128                   // partition blocks
#define FCHUNK ((ET + FB - 1) / FB)

typedef __attribute__((ext_vector_type(8))) short short8;
typedef __attribute__((ext_vector_type(4))) float f32x4;

__device__ __forceinline__ unsigned short f2bf(float f) {
    const unsigned u = __float_as_uint(f);
    return (unsigned short)((u + 0x7FFFu + ((u >> 16) & 1u)) >> 16);
}

// ---------------- CSR build: atomic-free 3-phase partition ----------------
__global__ __launch_bounds__(1024) void fill_count(const int* __restrict__ ei,
                                                   int* __restrict__ cntmat) {
    __shared__ int hist[NB];
    const int t = threadIdx.x, blk = blockIdx.x;
    for (int i = t; i < NB; i += 1024) hist[i] = 0;
    __syncthreads();
    const int s0 = blk * FCHUNK;
    const int s1 = min(s0 + FCHUNK, ET);
    for (int i = s0 + t; i < s1; i += 1024) {
        const int dst = (i < N_EDGES) ? ei[N_EDGES + i] : (i - N_EDGES);
        atomicAdd(&hist[dst >> BSH], 1);
    }
    __syncthreads();
    int* row = cntmat + (size_t)blk * NB;
    for (int i = t; i < NB; i += 1024) row[i] = hist[i];
}

__global__ __launch_bounds__(1024) void scan2(const int* __restrict__ cntmat,
                                              int* __restrict__ boff,
                                              int* __restrict__ basemat) {
    __shared__ int tot[2048];
    __shared__ int wsum[16];
    const int t = threadIdx.x;
    const int lane = t & 63;
    const int w = t >> 6;
    for (int b = t; b < 2048; b += 1024) {
        int s = 0;
        if (b < NB)
            for (int j = 0; j < FB; ++j) s += cntmat[(size_t)j * NB + b];
        tot[b] = s;
    }
    __syncthreads();
    int running = 0;
    for (int t0 = 0; t0 < 2048; t0 += 1024) {
        const int v = tot[t0 + t];
        int sc = v;
#pragma unroll
        for (int d = 1; d < 64; d <<= 1) {
            int u = __shfl_up(sc, d);
            if (lane >= d) sc += u;
        }
        if (lane == 63) wsum[w] = sc;
        __syncthreads();
        if (t < 16) {
            int ws = wsum[t];
#pragma unroll
            for (int d = 1; d < 16; d <<= 1) {
                int u = __shfl_up(ws, d);
                if (t >= d) ws += u;
            }
            wsum[t] = ws;
        }
        __syncthreads();
        const int excl = running + (w ? wsum[w - 1] : 0) + sc - v;
        if (t0 + t < NB) boff[t0 + t] = excl;
        const int tt = wsum[15];
        __syncthreads();
        tot[t0 + t] = excl;
        running += tt;
    }
    if (t == 0) boff[NB] = running;     // == ET
    __syncthreads();
    for (int b = t; b < NB; b += 1024) {
        int run = tot[b];
        for (int j = 0; j < FB; ++j) {
            basemat[(size_t)j * NB + b] = run;
            run += cntmat[(size_t)j * NB + b];
        }
    }
}

__global__ __launch_bounds__(1024) void fill_scatter(const int* __restrict__ ei,
                                                     const int* __restrict__ basemat,
                                                     unsigned int* __restrict__ ebuf) {
    __shared__ int cur[NB];
    const int t = threadIdx.x, blk = blockIdx.x;
    const int* row = basemat + (size_t)blk * NB;
    for (int i = t; i < NB; i += 1024) cur[i] = row[i];
    __syncthreads();
    const int s0 = blk * FCHUNK;
    const int s1 = min(s0 + FCHUNK, ET);
    for (int i = s0 + t; i < s1; i += 1024) {
        int src, dst;
        if (i < N_EDGES) { src = ei[i]; dst = ei[N_EDGES + i]; }
        else             { src = dst = i - N_EDGES; }
        const int b = dst >> BSH;
        const int p = atomicAdd(&cur[b], 1);
        ebuf[p] = (unsigned)src | ((unsigned)(dst & 63) << 17);
    }
}

// ---------------- W prep: W1[500][64] -> bf16 fragment-packed wpk ----------------
__global__ __launch_bounds__(256) void wprep(const float* __restrict__ W1,
                                             short* __restrict__ wpk) {
    const int idx = blockIdx.x * 256 + threadIdx.x;
    if (idx >= 32768) return;
    const int j = idx & 7;
    const int l = (idx >> 3) & 63;
    const int f = (idx >> 9) & 3;
    const int ks = idx >> 11;
    const int k = ks * 32 + ((l >> 4) << 3) + j;
    const int col = f * 16 + (l & 15);
    const float fv = (k < F_IN) ? W1[k * F1 + col] : 0.f;
    wpk[idx] = (short)f2bf(fv);
}

// ---------------- layer 1 GEMM: MFMA, split-A (hi+lo) x bf16-W ----------------
__global__ __launch_bounds__(256) void gemm1_kernel(
    const float* __restrict__ x, const short* __restrict__ wpk,
    const float* __restrict__ a_src, const float* __restrict__ a_dst,
    __half* __restrict__ h1, float* __restrict__ as1, float* __restrict__ ad1)
{
    const int t = threadIdx.x;
    const int l = t & 63;
    const int w = t >> 6;
    const int row0 = blockIdx.x * 64 + w * 16;
    const int r = l & 15;
    const int koff = (l >> 4) * 8;
    const float* __restrict__ xp =
        x + (size_t)min(row0 + r, N_NODES - 1) * F_IN + koff;
    const short* __restrict__ wl = wpk + (l << 3);

    f32x4 acc[4];
#pragma unroll
    for (int f = 0; f < 4; ++f) acc[f] = (f32x4){0.f, 0.f, 0.f, 0.f};

    float4 va = *(const float4*)(xp);
    float4 vb = *(const float4*)(xp + 4);
    short8 bcur[4];
#pragma unroll
    for (int f = 0; f < 4; ++f)
        bcur[f] = *(const short8*)(wl + (f << 9));

    for (int ks = 0; ks < 16; ++ks) {
        float v[8];
        v[0] = va.x; v[1] = va.y; v[2] = va.z; v[3] = va.w;
        v[4] = vb.x; v[5] = vb.y; v[6] = vb.z; v[7] = vb.w;
        if (ks < 14) {
            va = *(const float4*)(xp + (ks + 1) * 32);
            vb = *(const float4*)(xp + (ks + 1) * 32 + 4);
        } else if (ks == 14) {
            float tv[8];
#pragma unroll
            for (int j = 0; j < 8; ++j)
                tv[j] = (koff + j < 20) ? xp[480 + j] : 0.f;
            va = make_float4(tv[0], tv[1], tv[2], tv[3]);
            vb = make_float4(tv[4], tv[5], tv[6], tv[7]);
        }
        short8 bnext[4];
        if (ks < 15) {
#pragma unroll
            for (int f = 0; f < 4; ++f)
                bnext[f] = *(const short8*)(wl + (((ks + 1) * 4 + f) << 9));
        }
        short8 ah, al;
#pragma unroll
        for (int j = 0; j < 8; ++j) {
            const unsigned short h = f2bf(v[j]);
            ah[j] = (short)h;
            al[j] = (short)f2bf(v[j] - __uint_as_float((unsigned)h << 16));
        }
#pragma unroll
        for (int f = 0; f < 4; ++f) {
            acc[f] = __builtin_amdgcn_mfma_f32_16x16x32_bf16(ah, bcur[f], acc[f], 0, 0, 0);
            acc[f] = __builtin_amdgcn_mfma_f32_16x16x32_bf16(al, bcur[f], acc[f], 0, 0, 0);
        }
        if (ks < 15) {
#pragma unroll
            for (int f = 0; f < 4; ++f) bcur[f] = bnext[f];
        }
    }

    // epilogue: D[row][col], row = row0 + (l>>4)*4 + reg, col = f*16 + (l&15)
    const int g = l >> 4;
    const int p = r >> 3;
    float asv[4], adv[4];
#pragma unroll
    for (int f = 0; f < 4; ++f) {
        asv[f] = a_src[f * 16 + r];
        adv[f] = a_dst[f * 16 + r];
    }
#pragma unroll
    for (int f = 0; f < 4; ++f) {
#pragma unroll
        for (int reg = 0; reg < 4; ++reg) {
            const int row = row0 + g * 4 + reg;
            const float hv = acc[f][reg];
            if (row < N_NODES)
                h1[(size_t)row * F1 + f * 16 + r] = __float2half(hv);
            float ps = hv * asv[f];
            float pd = hv * adv[f];
            ps += __shfl_xor(ps, 1); ps += __shfl_xor(ps, 2); ps += __shfl_xor(ps, 4);
            pd += __shfl_xor(pd, 1); pd += __shfl_xor(pd, 2); pd += __shfl_xor(pd, 4);
            if ((l & 7) == 0 && row < N_NODES) {
                as1[row * H1 + f * 2 + p] = ps;
                ad1[row * H1 + f * 2 + p] = pd;
            }
        }
    }
}

// ---------------- layer 1 agg: block per bucket, LDS sort + register accum ----
// Sort (hist/scan/scatter, = old bucket_csr) puts src-sorted-by-dst in colb;
// then wave w aggregates nodes w*16..+15 with the 8x8 register scheme.
__global__ __launch_bounds__(256) void agg1_kernel(
    const int* __restrict__ boff, const unsigned int* __restrict__ ebuf,
    const __half* __restrict__ h1, const float* __restrict__ as1,
    const float* __restrict__ ad1, const float* __restrict__ b1,
    float* __restrict__ hout)
{
    __shared__ int colb[CAP2];
    __shared__ int hist[64], curs[64], rowp[65];
    const int t = threadIdx.x, b = blockIdx.x;
    const int e0 = boff[b];
    const int cnt = boff[b + 1] - e0;
    const int l = t & 63;
    const int w = t >> 6;
    if (t < 64) hist[t] = 0;
    __syncthreads();

    if (cnt <= CAP2) {
        for (int i = t; i < cnt; i += 256)
            atomicAdd(&hist[ebuf[e0 + i] >> 17], 1);
        __syncthreads();
        if (t < 64) {
            const int v = hist[t];
            int sc = v;
#pragma unroll
            for (int d = 1; d < 64; d <<= 1) {
                int u = __shfl_up(sc, d);
                if (t >= d) sc += u;
            }
            rowp[t] = sc - v;
            curs[t] = sc - v;
            if (t == 63) rowp[64] = sc;
        }
        __syncthreads();
        for (int i = t; i < cnt; i += 256) {
            const unsigned v = ebuf[e0 + i];
            const int p = atomicAdd(&curs[v >> 17], 1);
            colb[p] = (int)(v & 0x1FFFFu);
        }
        __syncthreads();

        const int jsub = l & 7;
        const int hsub = l >> 3;
        const int pbase = l & 56;
        for (int ni = 0; ni < 16; ++ni) {
            const int d = w * 16 + ni;
            const int n = (b << 6) + d;
            if (n >= N_NODES) break;            // wave-uniform
            const int rr0 = rowp[d], rr1 = rowp[d + 1];
            const float adh = ad1[(n << 3) + hsub];
            float den = 0.f, acc = 0.f;
            int j0 = rr0;
            for (; j0 + 8 <= rr1; j0 += 8) {
                const int s_l = colb[j0 + jsub];
                float e = as1[(s_l << 3) + hsub] + adh;
                e = fmaxf(e, 0.2f * e);
                const float p_l = __expf(e);
#pragma unroll
                for (int j = 0; j < 8; ++j) {
                    const float p = __shfl(p_l, pbase + j);
                    const int s_j = __builtin_amdgcn_readlane(s_l, j);
                    const float v = __half2float(h1[((size_t)(unsigned)s_j << 6) + l]);
                    den += p;
                    acc = fmaf(p, v, acc);
                }
            }
            if (j0 < rr1) {
                const int s_l = colb[min(j0 + jsub, rr1 - 1)];
                float e = as1[(s_l << 3) + hsub] + adh;
                e = fmaxf(e, 0.2f * e);
                const float p_l = __expf(e);
#pragma unroll
                for (int j = 0; j < 8; ++j) {
                    if (j0 + j < rr1) {
                        const float p = __shfl(p_l, pbase + j);
                        const int s_j = __builtin_amdgcn_readlane(s_l, j);
                        const float v = __half2float(h1[((size_t)(unsigned)s_j << 6) + l]);
                        den += p;
                        acc = fmaf(p, v, acc);
                    }
                }
            }
            hout[((size_t)n << 6) + l] = acc / den + b1[l];
        }
    } else {
        // fallback (statistically never): predicated full-bucket scan per node
        const int hsub = l >> 3;
        for (int ni = 0; ni < 16; ++ni) {
            const int d = w * 16 + ni;
            const int n = (b << 6) + d;
            if (n >= N_NODES) break;
            const float adh = ad1[(n << 3) + hsub];
            float den = 0.f, acc = 0.f;
            for (int i = 0; i < cnt; ++i) {
                const unsigned v = ebuf[e0 + i];
                if ((int)(v >> 17) == d) {
                    const int s = (int)(v & 0x1FFFFu);
                    float e = as1[(s << 3) + hsub] + adh;
                    e = fmaxf(e, 0.2f * e);
                    const float p = __expf(e);
                    const float hv = __half2float(h1[((size_t)s << 6) + l]);
                    den += p;
                    acc = fmaf(p, hv, acc);
                }
            }
            hout[((size_t)n << 6) + l] = acc / den + b1[l];
        }
    }
}

// ---------------- layer 2 GEMM + attention coefficients ----------------
__global__ __launch_bounds__(256) void gemm2_kernel(
    const float* __restrict__ hin, const float* __restrict__ W2,
    const float* __restrict__ a_src, const float* __restrict__ a_dst,
    float* __restrict__ h2p, float* __restrict__ as2, float* __restrict__ ad2)
{
    __shared__ float w2s[F1 * C2];
    __shared__ float as_s[C2], ad_s[C2];
    for (int i = threadIdx.x; i < F1 * C2; i += blockDim.x) w2s[i] = W2[i];
    if (threadIdx.x < C2) { as_s[threadIdx.x] = a_src[threadIdx.x]; ad_s[threadIdx.x] = a_dst[threadIdx.x]; }
    __syncthreads();

    int n = blockIdx.x * blockDim.x + threadIdx.x;
    if (n >= N_NODES) return;
    float acc[C2];
#pragma unroll
    for (int c = 0; c < C2; ++c) acc[c] = 0.f;
    const float* hp = hin + (size_t)n * F1;
    for (int k = 0; k < F1; k += 4) {
        const float4 hv = *(const float4*)(hp + k);
#pragma unroll
        for (int c = 0; c < C2; ++c) {
            acc[c] = fmaf(hv.x, w2s[(k + 0) * C2 + c], acc[c]);
            acc[c] = fmaf(hv.y, w2s[(k + 1) * C2 + c], acc[c]);
            acc[c] = fmaf(hv.z, w2s[(k + 2) * C2 + c], acc[c]);
            acc[c] = fmaf(hv.w, w2s[(k + 3) * C2 + c], acc[c]);
        }
    }
    float s = 0.f, d = 0.f;
#pragma unroll
    for (int c = 0; c < C2; ++c) {
        s = fmaf(acc[c], as_s[c], s);
        d = fmaf(acc[c], ad_s[c], d);
    }
    float4* o = (float4*)(h2p + (size_t)n * 8);
    o[0] = make_float4(acc[0], acc[1], acc[2], acc[3]);
    o[1] = make_float4(acc[4], acc[5], acc[6], 0.f);
    as2[n] = s;
    ad2[n] = d;
}

// ---------------- layer 2 agg: block per bucket, LDS sort + quarter-wave ----
__global__ __launch_bounds__(256) void agg2_kernel(
    const int* __restrict__ boff, const unsigned int* __restrict__ ebuf,
    const float* __restrict__ h2p, const float* __restrict__ as2,
    const float* __restrict__ ad2, const float* __restrict__ b2,
    float* __restrict__ out)
{
    __shared__ int colb[CAP2];
    __shared__ int hist[64], curs[64], rowp[65];
    const int t = threadIdx.x, b = blockIdx.x;
    const int e0 = boff[b];
    const int cnt = boff[b + 1] - e0;
    if (t < 64) hist[t] = 0;
    __syncthreads();

    const int d = t >> 2;             // node-in-bucket
    const int q = t & 3;
    const int n = (b << 6) + d;

    if (cnt <= CAP2) {
        for (int i = t; i < cnt; i += 256)
            atomicAdd(&hist[ebuf[e0 + i] >> 17], 1);
        __syncthreads();
        if (t < 64) {
            const int v = hist[t];
            int sc = v;
#pragma unroll
            for (int dd = 1; dd < 64; dd <<= 1) {
                int u = __shfl_up(sc, dd);
                if (t >= dd) sc += u;
            }
            rowp[t] = sc - v;
            curs[t] = sc - v;
            if (t == 63) rowp[64] = sc;
        }
        __syncthreads();
        for (int i = t; i < cnt; i += 256) {
            const unsigned v = ebuf[e0 + i];
            const int p = atomicAdd(&curs[v >> 17], 1);
            colb[p] = (int)(v & 0x1FFFFu);
        }
        __syncthreads();

        if (n >= N_NODES) return;
        const int rr0 = rowp[d], rr1 = rowp[d + 1];
        const float adn = ad2[n];
        float denom = 0.f;
        float a0 = 0, a1 = 0, a2 = 0, a3 = 0, a4 = 0, a5 = 0, a6 = 0;
        for (int j = rr0 + q; j < rr1; j += 4) {
            const int s = colb[j];
            float e = as2[s] + adn;
            e = fmaxf(e, 0.2f * e);
            const float ex = __expf(e);
            const float4 va = *(const float4*)(h2p + (size_t)s * 8);
            const float4 vb = *(const float4*)(h2p + (size_t)s * 8 + 4);
            denom += ex;
            a0 = fmaf(ex, va.x, a0); a1 = fmaf(ex, va.y, a1);
            a2 = fmaf(ex, va.z, a2); a3 = fmaf(ex, va.w, a3);
            a4 = fmaf(ex, vb.x, a4); a5 = fmaf(ex, vb.y, a5);
            a6 = fmaf(ex, vb.z, a6);
        }
#pragma unroll
        for (int dd = 1; dd < 4; dd <<= 1) {
            denom += __shfl_xor(denom, dd);
            a0 += __shfl_xor(a0, dd); a1 += __shfl_xor(a1, dd);
            a2 += __shfl_xor(a2, dd); a3 += __shfl_xor(a3, dd);
            a4 += __shfl_xor(a4, dd); a5 += __shfl_xor(a5, dd);
            a6 += __shfl_xor(a6, dd);
        }
        const float inv = 1.f / denom;
        float v0 = a0 * inv + b2[0], v1 = a1 * inv + b2[1];
        float v2 = a2 * inv + b2[2], v3 = a3 * inv + b2[3];
        float v4 = a4 * inv + b2[4], v5 = a5 * inv + b2[5];
        float v6 = a6 * inv + b2[6];
        float mx = fmaxf(fmaxf(fmaxf(v0, v1), fmaxf(v2, v3)), fmaxf(fmaxf(v4, v5), v6));
        const float se = __expf(v0 - mx) + __expf(v1 - mx) + __expf(v2 - mx) +
                         __expf(v3 - mx) + __expf(v4 - mx) + __expf(v5 - mx) +
                         __expf(v6 - mx);
        const float lse = __logf(se) + mx;
        const float wa = (q == 0) ? v0 : (q == 1) ? v1 : (q == 2) ? v2 : v3;
        const float wb = (q == 0) ? v4 : (q == 1) ? v5 : v6;
        out[n * C2 + q] = wa - lse;
        if (q < 3) out[n * C2 + q + 4] = wb - lse;
    } else {
        // fallback (statistically never): predicated full-bucket scan
        if (n >= N_NODES) return;
        const float adn = ad2[n];
        float denom = 0.f;
        float a0 = 0, a1 = 0, a2 = 0, a3 = 0, a4 = 0, a5 = 0, a6 = 0;
        for (int i = q; i < cnt; i += 4) {
            const unsigned v = ebuf[e0 + i];
            if ((int)(v >> 17) == d) {
                const int s = (int)(v & 0x1FFFFu);
                float e = as2[s] + adn;
                e = fmaxf(e, 0.2f * e);
                const float ex = __expf(e);
                const float4 va = *(const float4*)(h2p + (size_t)s * 8);
                const float4 vb = *(const float4*)(h2p + (size_t)s * 8 + 4);
                denom += ex;
                a0 = fmaf(ex, va.x, a0); a1 = fmaf(ex, va.y, a1);
                a2 = fmaf(ex, va.z, a2); a3 = fmaf(ex, va.w, a3);
                a4 = fmaf(ex, vb.x, a4); a5 = fmaf(ex, vb.y, a5);
                a6 = fmaf(ex, vb.z, a6);
            }
        }
#pragma unroll
        for (int dd = 1; dd < 4; dd <<= 1) {
            denom += __shfl_xor(denom, dd);
            a0 += __shfl_xor(a0, dd); a1 += __shfl_xor(a1, dd);
            a2 += __shfl_xor(a2, dd); a3 += __shfl_xor(a3, dd);
            a4 += __shfl_xor(a4, dd); a5 += __shfl_xor(a5, dd);
            a6 += __shfl_xor(a6, dd);
        }
        const float inv = 1.f / denom;
        float v0 = a0 * inv + b2[0], v1 = a1 * inv + b2[1];
        float v2 = a2 * inv + b2[2], v3 = a3 * inv + b2[3];
        float v4 = a4 * inv + b2[4], v5 = a5 * inv + b2[5];
        float v6 = a6 * inv + b2[6];
        float mx = fmaxf(fmaxf(fmaxf(v0, v1), fmaxf(v2, v3)), fmaxf(fmaxf(v4, v5), v6));
        const float se = __expf(v0 - mx) + __expf(v1 - mx) + __expf(v2 - mx) +
                         __expf(v3 - mx) + __expf(v4 - mx) + __expf(v5 - mx) +
                         __expf(v6 - mx);
        const float lse = __logf(se) + mx;
        const float wa = (q == 0) ? v0 : (q == 1) ? v1 : (q == 2) ? v2 : v3;
        const float wb = (q == 0) ? v4 : (q == 1) ? v5 : v6;
        out[n * C2 + q] = wa - lse;
        if (q < 3) out[n * C2 + q + 4] = wb - lse;
    }
}

extern "C" void kernel_launch(void* const* d_in, const int* in_sizes, int n_in,
                              void* d_out, int out_size, void* d_ws, size_t ws_size,
                              hipStream_t stream) {
    const float* x      = (const float*)d_in[0];
    const int*   ei     = (const int*)  d_in[1];
    const float* W1     = (const float*)d_in[2];
    const float* a_src1 = (const float*)d_in[3];
    const float* a_dst1 = (const float*)d_in[4];
    const float* b1     = (const float*)d_in[5];
    const float* W2     = (const float*)d_in[6];
    const float* a_src2 = (const float*)d_in[7];
    const float* a_dst2 = (const float*)d_in[8];
    const float* b2     = (const float*)d_in[9];
    float* out = (float*)d_out;

    char* ws = (char*)d_ws;
    size_t off = 0;
    auto alloc = [&](size_t bytes) -> void* {
        void* p = ws + off;
        off += (bytes + 255) & ~(size_t)255;
        return p;
    };
    int*          boff    = (int*)   alloc((size_t)(NB + 1) * sizeof(int));
    int*          cntmat  = (int*)   alloc((size_t)FB * NB * sizeof(int));
    int*          basemat = (int*)   alloc((size_t)FB * NB * sizeof(int));
    unsigned int* ebuf    = (unsigned int*)alloc((size_t)ET * sizeof(unsigned int));
    short*        wpk     = (short*) alloc((size_t)32768 * sizeof(short));
    __half*       h1      = (__half*)alloc((size_t)N_NODES * F1 * sizeof(__half));
    float*        as1     = (float*) alloc((size_t)N_NODES * H1 * sizeof(float));
    float*        ad1     = (float*) alloc((size_t)N_NODES * H1 * sizeof(float));
    float*        hout1   = (float*) alloc((size_t)N_NODES * F1 * sizeof(float));
    float*        h2p     = (float*) alloc((size_t)N_NODES * 8 * sizeof(float));
    float*        as2     = (float*) alloc((size_t)N_NODES * sizeof(float));
    float*        ad2     = (float*) alloc((size_t)N_NODES * sizeof(float));

    wprep<<<128, 256, 0, stream>>>(W1, wpk);
    fill_count<<<FB, 1024, 0, stream>>>(ei, cntmat);
    scan2<<<1, 1024, 0, stream>>>(cntmat, boff, basemat);
    fill_scatter<<<FB, 1024, 0, stream>>>(ei, basemat, ebuf);
    gemm1_kernel<<<(N_NODES + 63) / 64, 256, 0, stream>>>(x, wpk, a_src1, a_dst1, h1, as1, ad1);
    agg1_kernel<<<NB, 256, 0, stream>>>(boff, ebuf, h1, as1, ad1, b1, hout1);
    gemm2_kernel<<<(N_NODES + 255) / 256, 256, 0, stream>>>(hout1, W2, a_src2, a_dst2, h2p, as2, ad2);
    agg2_kernel<<<NB, 256, 0, stream>>>(boff, ebuf, h2p, as2, ad2, b2, out);
}